// Round 8
// baseline (280.900 us; speedup 1.0000x reference)
//
#include <hip/hip_runtime.h>
#include <hip/hip_bf16.h>

// 2-layer LSTM (H=32, T=512, I=1) + FC(1) + ReLU, fused, layer-pipelined at
// t4 granularity. Block = 128 threads = 2 waves: wave 0 = layer 0, wave 1 =
// layer 1 four steps behind (double-buffered LDS handoff, one __syncthreads
// per 4 steps). MFMA 16x16x32 bf16, NBW=4; lane (m,q,s) owns units
// 8m+2q+{0,1} of batch s; 3-cndmask gate select; bias in MFMA C-in; fused
// activations (8 trans/unit); x prefetched one t4 ahead.
// NEW vs R7: h B-fragment reassembly uses DPP row_ror (VALU, ~20cyc chain)
// instead of 4x ds_swizzle (DS pipe, ~150-250cyc latency in the recurrence
// chain); consumer MFMA order swapped so fresh-h1 MFMAs are last.

typedef __attribute__((ext_vector_type(8))) short bf16x8;
typedef __attribute__((ext_vector_type(4))) float f32x4;
typedef __attribute__((ext_vector_type(4))) int   i32x4;

#define HID 32
#define SEQ 512
#define NT4 (SEQ / 4)
#define NBW 4
#define L2E 1.4426950408889634f

static __device__ __forceinline__ float fexp2(float x){ return __builtin_amdgcn_exp2f(x); }
static __device__ __forceinline__ float frcp (float x){ return __builtin_amdgcn_rcpf(x); }
static __device__ __forceinline__ short f2bf(float f){
  unsigned u = __builtin_bit_cast(unsigned, f);
  u = (u + 0x7fffu + ((u >> 16) & 1u)) >> 16;
  return (short)u;
}

// gate (tau, unit 8m+2q+jj) lives at A[2*tau + (q>>1)][2*(q&1) + jj]
#define SEL(Atab, tau, jj) \
  ( khb ? ( rb ? Atab[2*(tau)+1][2+(jj)] : Atab[2*(tau)+1][(jj)] ) \
        : ( rb ? Atab[2*(tau)  ][2+(jj)] : Atab[2*(tau)  ][(jj)] ) )

// fused LSTM cell: gates pre-scaled (i,f,o by -log2e; g by +2log2e)
#define CELL(gi, gf, gg, go, cvr, hout) do {                         \
  const float I_ = fexp2(gi), G_ = fexp2(gg);                        \
  const float F_ = fexp2(gf), O_ = fexp2(go);                        \
  const float fv_ = frcp(1.f + F_);                                  \
  const float ig_ = (G_ - 1.f) * frcp((1.f + I_) * (1.f + G_));      \
  (cvr) = fmaf(fv_, (cvr), ig_);                                     \
  const float C2_ = fexp2((cvr) * (2.f * L2E));                      \
  (hout) = (C2_ - 1.f) * frcp((1.f + O_) * (1.f + C2_));             \
} while (0)

// Rebuild B-fragment from per-lane packed pair pk (units 8m+2q+{0,1} of
// batch s). Needed: hd[J] = pk of the lane with q=J (same m, s); lanes for
// one (m,s) sit at cols {s,4+s,8+s,12+s} within a 16-lane DPP row.
// row_ror:i => dst lane n reads lane n-i (mod 16): t_k = replica (q-k)&3.
// hd[J] = t_{(q-J)&3}  ==  rotate-right-by-q of (t0, t3, t2, t1).
static __device__ __forceinline__ i32x4 pack_bfrag(int pk, bool q1, bool q2) {
  const int t1 = __builtin_amdgcn_mov_dpp(pk, 0x124, 0xF, 0xF, false); // ror:4
  const int t2 = __builtin_amdgcn_mov_dpp(pk, 0x128, 0xF, 0xF, false); // ror:8
  const int t3 = __builtin_amdgcn_mov_dpp(pk, 0x12C, 0xF, 0xF, false); // ror:12
  // v = (t0, t3, t2, t1); u = q2 ? (v2,v3,v0,v1) : v
  const int u0 = q2 ? t2 : pk;
  const int u1 = q2 ? t1 : t3;
  const int u2 = q2 ? pk : t2;
  const int u3 = q2 ? t3 : t1;
  // hd = q1 ? (u3,u0,u1,u2) : (u0,u1,u2,u3)
  i32x4 hd;
  hd[0] = q1 ? u3 : u0;
  hd[1] = q1 ? u0 : u1;
  hd[2] = q1 ? u1 : u2;
  hd[3] = q1 ? u2 : u3;
  return hd;
}

__global__ __launch_bounds__(128, 2) void lstm2_pipe4d_kernel(
    const float* __restrict__ x,
    const float* __restrict__ Wih0, const float* __restrict__ Whh0,
    const float* __restrict__ bih0, const float* __restrict__ bhh0,
    const float* __restrict__ Wih1, const float* __restrict__ Whh1,
    const float* __restrict__ bih1, const float* __restrict__ bhh1,
    const float* __restrict__ Wfc, const float* __restrict__ bfc,
    float* __restrict__ out)
{
  const int tid = threadIdx.x;
  const int w   = tid >> 6;        // 0: layer-0 producer, 1: layer-1 consumer
  const int l   = tid & 63;
  const int m   = l >> 4;          // A/B fragment k-group
  const int col = l & 15;          // MFMA N col
  const int q   = col >> 2;        // replication group -> units 8m+2q+{0,1}
  const int s   = col & 3;         // batch slot
  const int batch = blockIdx.x * NBW + s;
  const bool khb = ((q >> 1) & 1) != 0;
  const bool rb  = (q & 1) != 0;
  const bool q1  = rb, q2 = khb;   // pack_bfrag selectors

  __shared__ i32x4 hbuf[2][4][64];   // double-buffered 4-step h0 B-frags, 8 KiB

  // ---- weight fragments (A), rows pre-scaled: i,f,o -> -log2e; g -> +2log2e
  bf16x8 wfA[8], wfB[8];   // w0: wfA=Whh0; w1: wfA=Wih1, wfB=Whh1
  f32x4 cb[8];             // MFMA C-in: per-slot gate bias (pre-scaled)
  #pragma unroll
  for (int c = 0; c < 8; ++c) {
    const int tau = c >> 1, kh = c & 1;
    const float sc = (tau == 2) ? (2.0f * L2E) : (-L2E);
    const int ga = tau * 32 + (q << 3) + (kh << 2) + s;   // A-row = col packing
    if (w == 0) {
      #pragma unroll
      for (int j = 0; j < 8; ++j)
        wfA[c][j] = f2bf(sc * Whh0[ga * HID + (m * 8 + j)]);
    } else {
      #pragma unroll
      for (int j = 0; j < 8; ++j) {
        wfA[c][j] = f2bf(sc * Wih1[ga * HID + (m * 8 + j)]);
        wfB[c][j] = f2bf(sc * Whh1[ga * HID + (m * 8 + j)]);
      }
    }
    #pragma unroll
    for (int r = 0; r < 4; ++r) {    // bias of D-slot (c,r)
      const int g = tau * 32 + 8 * m + 4 * kh + r;
      cb[c][r] = sc * (w == 0 ? (bih0[g] + bhh0[g]) : (bih1[g] + bhh1[g]));
    }
  }

  // ---- per-lane constants for owned units u = 8m+2q+jj
  float w0x[4][2];   // w0: sc * Wih0[tau*32+u]
  float wfcA = 0.f, wfcB = 0.f;
  if (w == 0) {
    #pragma unroll
    for (int tau = 0; tau < 4; ++tau) {
      const float sc = (tau == 2) ? (2.0f * L2E) : (-L2E);
      #pragma unroll
      for (int jj = 0; jj < 2; ++jj)
        w0x[tau][jj] = sc * Wih0[tau * 32 + 8 * m + 2 * q + jj];
    }
  } else {
    wfcA = Wfc[8 * m + 2 * q];
    wfcB = Wfc[8 * m + 2 * q + 1];
  }

  bf16x8 hf = {};                 // w0: own h0 frag; w1: own h1 frag
  float cv[2] = {0.f, 0.f};
  float hn0 = 0.f, hn1 = 0.f;

  const float* xb = x + (size_t)batch * SEQ;
  float4 xcur = {0.f, 0.f, 0.f, 0.f};
  if (w == 0) xcur = *reinterpret_cast<const float4*>(xb);

  for (int k = 0; k <= NT4; ++k) {
    float4 xnext = {0.f, 0.f, 0.f, 0.f};
    if (w == 0 && k + 1 < NT4)
      xnext = *reinterpret_cast<const float4*>(xb + (k + 1) * 4);  // prefetch

    if (w == 0 && k < NT4) {
      // ---------- producer: 4 steps of layer 0 into set k&1 ----------
      #pragma unroll
      for (int uu = 0; uu < 4; ++uu) {
        const float xt = (uu == 0) ? xcur.x : (uu == 1) ? xcur.y
                       : (uu == 2) ? xcur.z : xcur.w;
        f32x4 A[8];
        #pragma unroll
        for (int c = 0; c < 8; ++c)   // D = Whh0*h0 + bias (C-in)
          A[c] = __builtin_amdgcn_mfma_f32_16x16x32_bf16(wfA[c], hf, cb[c], 0, 0, 0);
        #pragma unroll
        for (int jj = 0; jj < 2; ++jj) {
          const float gi = fmaf(w0x[0][jj], xt, SEL(A, 0, jj));
          const float gf = fmaf(w0x[1][jj], xt, SEL(A, 1, jj));
          const float gg = fmaf(w0x[2][jj], xt, SEL(A, 2, jj));
          const float go = fmaf(w0x[3][jj], xt, SEL(A, 3, jj));
          float hn;
          CELL(gi, gf, gg, go, cv[jj], hn);
          if (jj == 0) hn0 = hn; else hn1 = hn;
        }
        int pk;
        asm("v_cvt_pk_bf16_f32 %0, %1, %2" : "=v"(pk) : "v"(hn0), "v"(hn1));
        const i32x4 hd = pack_bfrag(pk, q1, q2);   // VALU-only reassembly
        hf = __builtin_bit_cast(bf16x8, hd);
        hbuf[k & 1][uu][l] = hd;       // publish B-fragment for wave 1
      }
    }
    if (w == 1 && k > 0) {
      // ---------- consumer: 4 steps of layer 1 from set (k-1)&1 ----------
      i32x4 hd4[4];
      #pragma unroll
      for (int uu = 0; uu < 4; ++uu) hd4[uu] = hbuf[(k - 1) & 1][uu][l];
      #pragma unroll
      for (int uu = 0; uu < 4; ++uu) {
        const bf16x8 h0f = __builtin_bit_cast(bf16x8, hd4[uu]);
        f32x4 A[8];
        __builtin_amdgcn_s_setprio(1);
        #pragma unroll
        for (int c = 0; c < 8; ++c)   // LDS-sourced (prefetched) MFMA first
          A[c] = __builtin_amdgcn_mfma_f32_16x16x32_bf16(wfA[c], h0f, cb[c], 0, 0, 0);
        #pragma unroll
        for (int c = 0; c < 8; ++c)   // fresh-h1 (recurrent) MFMA last
          A[c] = __builtin_amdgcn_mfma_f32_16x16x32_bf16(wfB[c], hf, A[c], 0, 0, 0);
        __builtin_amdgcn_s_setprio(0);
        #pragma unroll
        for (int jj = 0; jj < 2; ++jj) {
          const float gi = SEL(A, 0, jj);
          const float gf = SEL(A, 1, jj);
          const float gg = SEL(A, 2, jj);
          const float go = SEL(A, 3, jj);
          float hn;
          CELL(gi, gf, gg, go, cv[jj], hn);
          if (jj == 0) hn0 = hn; else hn1 = hn;
        }
        int pk;
        asm("v_cvt_pk_bf16_f32 %0, %1, %2" : "=v"(pk) : "v"(hn0), "v"(hn1));
        const i32x4 hd1 = pack_bfrag(pk, q1, q2);
        hf = __builtin_bit_cast(bf16x8, hd1);
      }
    }
    __syncthreads();
    xcur = xnext;
  }

  // ---- FC + ReLU (wave 1 holds h1(T-1) in hn0/hn1) ----
  if (w == 1) {
    float part = hn0 * wfcA + hn1 * wfcB;
    part += __shfl_xor(part, 4);
    part += __shfl_xor(part, 8);
    part += __shfl_xor(part, 16);
    part += __shfl_xor(part, 32);
    if (l < 4) {
      const float o = part + bfc[0];
      out[blockIdx.x * NBW + l] = o > 0.f ? o : 0.f;
    }
  }
}

extern "C" void kernel_launch(void* const* d_in, const int* in_sizes, int n_in,
                              void* d_out, int out_size, void* d_ws, size_t ws_size,
                              hipStream_t stream) {
  const float* x    = (const float*)d_in[0];
  const float* Wih0 = (const float*)d_in[1];
  const float* Whh0 = (const float*)d_in[2];
  const float* bih0 = (const float*)d_in[3];
  const float* bhh0 = (const float*)d_in[4];
  const float* Wih1 = (const float*)d_in[5];
  const float* Whh1 = (const float*)d_in[6];
  const float* bih1 = (const float*)d_in[7];
  const float* bhh1 = (const float*)d_in[8];
  const float* Wfc  = (const float*)d_in[9];
  const float* bfc  = (const float*)d_in[10];

  const int B = 4096;
  const int grid = B / NBW;   // 1024 blocks x 2 waves -> 2 waves/SIMD
  lstm2_pipe4d_kernel<<<grid, 128, 0, stream>>>(
      x, Wih0, Whh0, bih0, bhh0, Wih1, Whh1, bih1, bhh1, Wfc, bfc,
      (float*)d_out);
}

// Round 9
// 268.425 us; speedup vs baseline: 1.0465x; 1.0465x over previous
//
#include <hip/hip_runtime.h>
#include <hip/hip_bf16.h>

// 2-layer LSTM (H=32, T=512, I=1) + FC(1) + ReLU, fused, 4-wave unit-split.
// Block = 256 threads = 4 waves: w0/w1 = layer-0 units 0-15/16-31,
// w2/w3 = layer-1 units 0-15/16-31 (one step behind). Each wave: 4 gate
// tiles (M=16 rows each) of its 64 gate rows -> 4 MFMA (L0) / 8 MFMA (L1)
// 16x16x32 bf16 per step; identity row permutation puts gate (tau, unit
// 16U+4m+q) at D slot (tau,q) -> 3-cndmask select; cell update lane-local.
// h exchanged as packed bf16 pairs via LDS (double-buffered by parity,
// ONE __syncthreads per step). Bias in MFMA C-in; fused activations;
// pre-zeroed LDS kills all t=0 special cases. 4096 waves = 4/SIMD.

typedef __attribute__((ext_vector_type(8))) short bf16x8;
typedef __attribute__((ext_vector_type(4))) float f32x4;
typedef __attribute__((ext_vector_type(4))) int   i32x4;

#define HID 32
#define SEQ 512
#define L2E 1.4426950408889634f

static __device__ __forceinline__ float fexp2(float x){ return __builtin_amdgcn_exp2f(x); }
static __device__ __forceinline__ float frcp (float x){ return __builtin_amdgcn_rcpf(x); }
static __device__ __forceinline__ short f2bf(float f){
  unsigned u = __builtin_bit_cast(unsigned, f);
  u = (u + 0x7fffu + ((u >> 16) & 1u)) >> 16;
  return (short)u;
}

// fused LSTM cell: gates pre-scaled (i,f,o by -log2e; g by +2log2e)
#define CELL(gi, gf, gg, go, cvr, hout) do {                         \
  const float I_ = fexp2(gi), G_ = fexp2(gg);                        \
  const float F_ = fexp2(gf), O_ = fexp2(go);                        \
  const float fv_ = frcp(1.f + F_);                                  \
  const float ig_ = (G_ - 1.f) * frcp((1.f + I_) * (1.f + G_));      \
  (cvr) = fmaf(fv_, (cvr), ig_);                                     \
  const float C2_ = fexp2((cvr) * (2.f * L2E));                      \
  (hout) = (C2_ - 1.f) * frcp((1.f + O_) * (1.f + C2_));             \
} while (0)

__global__ __launch_bounds__(256, 4) void lstm2_us4_kernel(
    const float* __restrict__ x,
    const float* __restrict__ Wih0, const float* __restrict__ Whh0,
    const float* __restrict__ bih0, const float* __restrict__ bhh0,
    const float* __restrict__ Wih1, const float* __restrict__ Whh1,
    const float* __restrict__ bih1, const float* __restrict__ bhh1,
    const float* __restrict__ Wfc, const float* __restrict__ bfc,
    float* __restrict__ out)
{
  const int tid = threadIdx.x;
  const int w   = tid >> 6;          // 0,1: L0 halves; 2,3: L1 halves
  const int l   = tid & 63;
  const int m   = l >> 4;            // A/B fragment k-group (units 8m..8m+7)
  const int col = l & 15;            // MFMA N col
  const int q   = col >> 2;          // D row-subselect -> owned unit
  const int s   = col & 3;           // batch slot
  const int U   = w & 1;             // unit half
  const int batch = blockIdx.x * 4 + s;
  const int unit  = 16 * U + 4 * m + q;   // owned unit within layer

  __shared__ int   bufH0[2][64];     // packed h pairs: [parity][s*16 + pair]
  __shared__ int   bufH1[2][64];
  __shared__ float bufFC[2][4];

  // zero-init exchange buffers (kills all t=0 special cases)
  { int* bz = (w < 2) ? &bufH0[U][0] : &bufH1[U][0]; bz[l] = 0; }
  __syncthreads();

  // ---- weights: tile tau row rho = gate (tau, unit 16U+rho); lane supplies
  //      A row=col. Rows pre-scaled: i,f,o -> -log2e; g -> +2log2e.
  bf16x8 wfR[4], wfI[4];   // recurrent (Whh) / L1-input (Wih1) fragments
  f32x4  cb[4];            // MFMA C-in: per-slot gate bias (pre-scaled)
  float  w0x[4];           // L0: sc * Wih0 for owned unit
  const float* Wrec = (w < 2) ? Whh0 : Whh1;
  const float* Bi   = (w < 2) ? bih0 : bih1;
  const float* Bh   = (w < 2) ? bhh0 : bhh1;
  #pragma unroll
  for (int t = 0; t < 4; ++t) {
    const float sc = (t == 2) ? (2.0f * L2E) : (-L2E);
    const int ga = t * 32 + 16 * U + col;
    #pragma unroll
    for (int j = 0; j < 8; ++j) {
      wfR[t][j] = f2bf(sc * Wrec[ga * HID + (8 * m + j)]);
      wfI[t][j] = (w >= 2) ? f2bf(sc * Wih1[ga * HID + (8 * m + j)]) : (short)0;
    }
    #pragma unroll
    for (int r = 0; r < 4; ++r) {
      const int g = t * 32 + 16 * U + 4 * m + r;
      cb[t][r] = sc * (Bi[g] + Bh[g]);
    }
    w0x[t] = (w < 2) ? sc * Wih0[t * 32 + unit] : 0.f;
  }
  const float wfc = (w >= 2) ? Wfc[unit] : 0.f;

  float cv = 0.f, hn = 0.f;
  const float* xb = x + (size_t)batch * SEQ;
  const int  rdA = s * 16 + 4 * m;                      // b128 read: pairs 4m..4m+3
  const int  wrP = s * 16 + 8 * U + 2 * m + (q >> 1);   // b32 write: own pair
  const bool wr  = ((q & 1) == 0);                      // even-q lanes write

  for (int k = 0; k < SEQ / 4; ++k) {
    float4 xv = {0.f, 0.f, 0.f, 0.f};
    if (w < 2) xv = *reinterpret_cast<const float4*>(xb + k * 4);
    #pragma unroll
    for (int uu = 0; uu < 4; ++uu) {
      const int par = (k * 4 + uu) & 1;        // i & 1
      if (w < 2) {
        // ---- L0: compute h0(i); reads h0(i-1) at parity (i+1)&1 ----
        const i32x4 hv = *(const i32x4*)&bufH0[par ^ 1][rdA];
        const bf16x8 hf = __builtin_bit_cast(bf16x8, hv);
        f32x4 A[4];
        #pragma unroll
        for (int t = 0; t < 4; ++t)
          A[t] = __builtin_amdgcn_mfma_f32_16x16x32_bf16(wfR[t], hf, cb[t], 0, 0, 0);
        const float xt = (uu == 0) ? xv.x : (uu == 1) ? xv.y : (uu == 2) ? xv.z : xv.w;
        float g4[4];
        #pragma unroll
        for (int t = 0; t < 4; ++t) {
          const float e = (q & 1) ? A[t][1] : A[t][0];
          const float o = (q & 1) ? A[t][3] : A[t][2];
          g4[t] = fmaf(w0x[t], xt, (q & 2) ? o : e);
        }
        CELL(g4[0], g4[1], g4[2], g4[3], cv, hn);
        // pair-pack with unit+1 (lane col+4): DPP row_ror:12 (dst n <- n+4)
        const float hp = __builtin_bit_cast(float,
            __builtin_amdgcn_mov_dpp(__builtin_bit_cast(int, hn), 0x12C, 0xF, 0xF, false));
        int pk;
        asm("v_cvt_pk_bf16_f32 %0, %1, %2" : "=v"(pk) : "v"(hn), "v"(hp));
        if (wr) bufH0[par][wrP] = pk;
      } else if (uu > 0 || k > 0) {
        // ---- L1: compute h1(i-1); reads h0(i-1) par^1, h1(i-2) par ----
        const i32x4 h0v = *(const i32x4*)&bufH0[par ^ 1][rdA];
        const i32x4 h1v = *(const i32x4*)&bufH1[par][rdA];
        const bf16x8 h0f = __builtin_bit_cast(bf16x8, h0v);
        const bf16x8 h1f = __builtin_bit_cast(bf16x8, h1v);
        f32x4 A[4];
        __builtin_amdgcn_s_setprio(1);
        #pragma unroll
        for (int t = 0; t < 4; ++t)
          A[t] = __builtin_amdgcn_mfma_f32_16x16x32_bf16(wfR[t], h1f, cb[t], 0, 0, 0);
        #pragma unroll
        for (int t = 0; t < 4; ++t)
          A[t] = __builtin_amdgcn_mfma_f32_16x16x32_bf16(wfI[t], h0f, A[t], 0, 0, 0);
        __builtin_amdgcn_s_setprio(0);
        float g4[4];
        #pragma unroll
        for (int t = 0; t < 4; ++t) {
          const float e = (q & 1) ? A[t][1] : A[t][0];
          const float o = (q & 1) ? A[t][3] : A[t][2];
          g4[t] = (q & 2) ? o : e;
        }
        CELL(g4[0], g4[1], g4[2], g4[3], cv, hn);
        const float hp = __builtin_bit_cast(float,
            __builtin_amdgcn_mov_dpp(__builtin_bit_cast(int, hn), 0x12C, 0xF, 0xF, false));
        int pk;
        asm("v_cvt_pk_bf16_f32 %0, %1, %2" : "=v"(pk) : "v"(hn), "v"(hp));
        if (wr) bufH1[par ^ 1][wrP] = pk;   // h1(i-1) -> parity (i-1)&1
      }
      __syncthreads();
    }
  }

  // ---- epilogue: i = 512 for L1 -> h1(511); then FC + ReLU ----
  if (w >= 2) {
    const i32x4 h0v = *(const i32x4*)&bufH0[1][rdA];   // h0(511), parity 1
    const i32x4 h1v = *(const i32x4*)&bufH1[0][rdA];   // h1(510), parity 0
    const bf16x8 h0f = __builtin_bit_cast(bf16x8, h0v);
    const bf16x8 h1f = __builtin_bit_cast(bf16x8, h1v);
    f32x4 A[4];
    #pragma unroll
    for (int t = 0; t < 4; ++t)
      A[t] = __builtin_amdgcn_mfma_f32_16x16x32_bf16(wfR[t], h1f, cb[t], 0, 0, 0);
    #pragma unroll
    for (int t = 0; t < 4; ++t)
      A[t] = __builtin_amdgcn_mfma_f32_16x16x32_bf16(wfI[t], h0f, A[t], 0, 0, 0);
    float g4[4];
    #pragma unroll
    for (int t = 0; t < 4; ++t) {
      const float e = (q & 1) ? A[t][1] : A[t][0];
      const float o = (q & 1) ? A[t][3] : A[t][2];
      g4[t] = (q & 2) ? o : e;
    }
    CELL(g4[0], g4[1], g4[2], g4[3], cv, hn);
    float part = hn * wfc;
    part += __shfl_xor(part, 4);
    part += __shfl_xor(part, 8);
    part += __shfl_xor(part, 16);
    part += __shfl_xor(part, 32);
    if (l < 4) bufFC[U][l] = part;
  }
  __syncthreads();
  if (w == 2 && l < 4) {
    const float o = bufFC[0][l] + bufFC[1][l] + bfc[0];
    out[blockIdx.x * 4 + l] = o > 0.f ? o : 0.f;
  }
}

extern "C" void kernel_launch(void* const* d_in, const int* in_sizes, int n_in,
                              void* d_out, int out_size, void* d_ws, size_t ws_size,
                              hipStream_t stream) {
  const float* x    = (const float*)d_in[0];
  const float* Wih0 = (const float*)d_in[1];
  const float* Whh0 = (const float*)d_in[2];
  const float* bih0 = (const float*)d_in[3];
  const float* bhh0 = (const float*)d_in[4];
  const float* Wih1 = (const float*)d_in[5];
  const float* Whh1 = (const float*)d_in[6];
  const float* bih1 = (const float*)d_in[7];
  const float* bhh1 = (const float*)d_in[8];
  const float* Wfc  = (const float*)d_in[9];
  const float* bfc  = (const float*)d_in[10];

  const int B = 4096;
  const int grid = B / 4;   // 1024 blocks x 4 waves = 4096 waves -> 4/SIMD
  lstm2_us4_kernel<<<grid, 256, 0, stream>>>(
      x, Wih0, Whh0, bih0, bhh0, Wih1, Whh1, bih1, bhh1, Wfc, bfc,
      (float*)d_out);
}